// Round 4
// baseline (58.098 us; speedup 1.0000x reference)
//
#include <hip/hip_runtime.h>

#define N_CELLS   16384
#define N_CLASSES 64
#define BATCH     64
#define CPB       4   // cells per block

typedef float f32x4 __attribute__((ext_vector_type(4)));
typedef float f32x2 __attribute__((ext_vector_type(2)));

// log2(e) * 4/3 : exp(-(4/3)x) == exp2(-1.9235933878x)
#define K_EXP 1.9235933878f

__global__ __launch_bounds__(256) void mnl_kernel(
    const float* __restrict__ x,     // (B, N)
    const float* __restrict__ w,     // (N, C, 3)
    const float* __restrict__ bias,  // (N, C)
    float* __restrict__ out)         // (B, N, C)
{
    const int t    = threadIdx.x;
    const int lane = t & 63;
    const int wid  = t >> 6;              // wave id 0..3 -> batch phase
    const int di   = lane >> 4;           // cell within block, 0..3
    const int c4   = (lane & 15) * 4;     // class group
    const int i    = blockIdx.x * CPB + di;

    const int il = (i == 0)           ? N_CELLS - 1 : i - 1;
    const int ir = (i == N_CELLS - 1) ? 0           : i + 1;

    // ---- per-thread weights: 12 consecutive floats (16B aligned) ----
    const float4* wv = reinterpret_cast<const float4*>(
        w + (size_t)i * (N_CLASSES * 3) + (size_t)c4 * 3);
    const float4 v0 = wv[0], v1 = wv[1], v2 = wv[2];
    // class j: w0=wr[3j], w1=wr[3j+1], w2=wr[3j+2]; pack as pairs (cls 0,1) (cls 2,3)
    const f32x2 w0a = { v0.x, v0.w };   // k=0: cls0, cls1
    const f32x2 w1a = { v0.y, v1.x };   // k=1
    const f32x2 w2a = { v0.z, v1.y };   // k=2
    const f32x2 w0b = { v1.z, v2.y };   // k=0: cls2, cls3
    const f32x2 w1b = { v1.w, v2.z };   // k=1
    const f32x2 w2b = { v2.x, v2.w };   // k=2

    const float4 bi = *reinterpret_cast<const float4*>(
        bias + (size_t)i * N_CLASSES + c4);
    const f32x2 ba = { bi.x, bi.y };
    const f32x2 bb = { bi.z, bi.w };

    #pragma unroll 4
    for (int p = 0; p < 16; ++p) {
        const int b = p * 4 + wid;
        const size_t xb = (size_t)b * N_CELLS;

        const float xl = x[xb + il];
        const float xc = x[xb + i];
        const float xr = x[xb + ir];
        const f32x2 xl2 = { xl, xl }, xc2 = { xc, xc }, xr2 = { xr, xr };

        // packed score FMAs (v_pk_fma_f32)
        f32x2 sa = xl2 * w0a + xc2 * w1a + xr2 * w2a + ba;
        f32x2 sb = xl2 * w0b + xc2 * w1b + xr2 * w2b + bb;

        // e = exp2(-K*|s|)  (abs folds as VOP modifier into the mul)
        float e0 = __builtin_amdgcn_exp2f(-K_EXP * fabsf(sa.x));
        float e1 = __builtin_amdgcn_exp2f(-K_EXP * fabsf(sa.y));
        float e2 = __builtin_amdgcn_exp2f(-K_EXP * fabsf(sb.x));
        float e3 = __builtin_amdgcn_exp2f(-K_EXP * fabsf(sb.y));

        // d = 1 + e (packed)
        f32x4 e4 = { e0, e1, e2, e3 };
        f32x4 d4 = e4 + 1.0f;

        // r = 1/d (v_rcp_f32)
        f32x4 r4 = { __builtin_amdgcn_rcpf(d4.x), __builtin_amdgcn_rcpf(d4.y),
                     __builtin_amdgcn_rcpf(d4.z), __builtin_amdgcn_rcpf(d4.w) };

        // |out| = 3.4318*r - 1.7159  (packed fma); then restore sign of s
        f32x4 mag = 3.4318f * r4 - 1.7159f;

        f32x4 o;
        o.x = copysignf(mag.x, sa.x);
        o.y = copysignf(mag.y, sa.y);
        o.z = copysignf(mag.z, sb.x);
        o.w = copysignf(mag.w, sb.y);

        f32x4* op = reinterpret_cast<f32x4*>(
            out + ((size_t)b * N_CELLS + i) * N_CLASSES + c4);
        __builtin_nontemporal_store(o, op);
    }
}

extern "C" void kernel_launch(void* const* d_in, const int* in_sizes, int n_in,
                              void* d_out, int out_size, void* d_ws, size_t ws_size,
                              hipStream_t stream) {
    const float* x    = (const float*)d_in[0];  // (64, 16384, 1)
    const float* w    = (const float*)d_in[1];  // (16384, 64, 3)
    const float* bias = (const float*)d_in[2];  // (16384, 64)
    float* out = (float*)d_out;                 // (64, 16384, 64)

    dim3 grid(N_CELLS / CPB);
    dim3 block(256);
    mnl_kernel<<<grid, block, 0, stream>>>(x, w, bias, out);
}